// Round 1
// baseline (407.046 us; speedup 1.0000x reference)
//
#include <hip/hip_runtime.h>
#include <math.h>

#define D 128
#define W 65            // D/2+1
#define NK 125
#define NB 8
#define SLAB (D*W)      // 8320 complex elements per (z or particle) slab
#define CHUNK 13        // 65 = 5*13, x-chunk for corr kernel
#define TWO_PI 6.28318530717958647692f

// ---------------- helpers ----------------

__device__ __forceinline__ bool better(float va, int ia, float vb, int ib) {
    return (va > vb) || (va == vb && ia < ib);
}

// ---------------- rotation matrices ----------------

__global__ void rot_kernel(const float* __restrict__ euler, float* __restrict__ rot) {
    int k = blockIdx.x * blockDim.x + threadIdx.x;
    if (k >= NK) return;
    const float d2r = 0.017453292519943295f;
    float a = euler[k*3+0] * d2r, b = euler[k*3+1] * d2r, c = euler[k*3+2] * d2r;
    float sa, ca, sb, cb, sc, cc;
    sincosf(a, &sa, &ca);
    sincosf(b, &sb, &cb);
    sincosf(c, &sc, &cc);
    // R = Rz(a) @ Ry(b) @ Rz(c)
    rot[k*9+0] =  ca*cb*cc - sa*sc;
    rot[k*9+1] = -ca*cb*sc - sa*cc;
    rot[k*9+2] =  ca*sb;
    rot[k*9+3] =  sa*cb*cc + ca*sc;
    rot[k*9+4] = -sa*cb*sc + ca*cc;
    rot[k*9+5] =  sa*sb;
    rot[k*9+6] = -sb*cc;
    rot[k*9+7] =  sb*sc;
    rot[k*9+8] =  cb;
}

// ---------------- forward transforms (naive DFT, LDS-staged) ----------------

// real rows of length 128 -> 65 complex bins. One block (128 thr) per row.
__global__ void rfft_rows(const float* __restrict__ in, float2* __restrict__ out, int nrows) {
    __shared__ float row[D];
    __shared__ float2 tw[D];   // e^{-2*pi*i*n/128}
    int r = blockIdx.x;
    int t = threadIdx.x;
    row[t] = in[r*D + t];
    {
        float s, c;
        sincosf(-TWO_PI * (float)t / (float)D, &s, &c);
        tw[t] = make_float2(c, s);
    }
    __syncthreads();
    if (t < W) {
        float ar = 0.f, ai = 0.f;
        for (int x = 0; x < D; ++x) {
            float2 w = tw[(x * t) & (D-1)];
            float v = row[x];
            ar = fmaf(v, w.x, ar);
            ai = fmaf(v, w.y, ai);
        }
        out[r*W + t] = make_float2(ar, ai);
    }
}

// complex FFT over the middle (y) axis of [S][128][65], fftshift folded into
// the write: out index b holds frequency (b+64)%128. One block per (s, x') line.
__global__ void fft_y_shift(const float2* __restrict__ in, float2* __restrict__ out) {
    __shared__ float2 col[D];
    __shared__ float2 tw[D];   // e^{-2*pi*i*n/128}
    int l = blockIdx.x;
    int t = threadIdx.x;
    int base = (l / W) * SLAB + (l % W);
    col[t] = in[base + t * W];
    {
        float s, c;
        sincosf(-TWO_PI * (float)t / (float)D, &s, &c);
        tw[t] = make_float2(c, s);
    }
    __syncthreads();
    int bp = (t + 64) & (D-1);   // shifted frequency index
    float ar = 0.f, ai = 0.f;
    for (int y = 0; y < D; ++y) {
        float2 p = col[y];
        float2 w = tw[(y * bp) & (D-1)];
        ar += p.x*w.x - p.y*w.y;
        ai += p.x*w.y + p.y*w.x;
    }
    out[base + t * W] = make_float2(ar, ai);
}

// complex FFT over the z axis of [128][128][65], fftshift folded into write.
// One block per (b, x') line (8320 lines).
__global__ void fft_z_shift(const float2* __restrict__ in, float2* __restrict__ out) {
    __shared__ float2 col[D];
    __shared__ float2 tw[D];
    int l = blockIdx.x;   // 0..SLAB-1
    int t = threadIdx.x;
    col[t] = in[t * SLAB + l];
    {
        float s, c;
        sincosf(-TWO_PI * (float)t / (float)D, &s, &c);
        tw[t] = make_float2(c, s);
    }
    __syncthreads();
    int ap = (t + 64) & (D-1);
    float ar = 0.f, ai = 0.f;
    for (int z = 0; z < D; ++z) {
        float2 p = col[z];
        float2 w = tw[(z * ap) & (D-1)];
        ar += p.x*w.x - p.y*w.y;
        ai += p.x*w.y + p.y*w.x;
    }
    out[t * SLAB + l] = make_float2(ar, ai);
}

// ---------------- central-slice projection ----------------

__global__ void proj_kernel(const float2* __restrict__ vol, const float* __restrict__ rot,
                            float2* __restrict__ projs) {
    int idx = blockIdx.x * blockDim.x + threadIdx.x;
    if (idx >= NK * D * W) return;
    int w = idx % W;
    int h = (idx / W) % D;
    int k = idx / (D * W);
    float x = (float)w;
    float y = (float)(h - 64);
    const float* R = rot + k*9;
    float rx = R[0]*x + R[1]*y;
    float ry = R[3]*x + R[4]*y;
    float rz = R[6]*x + R[7]*y;
    bool neg = rx < 0.0f;
    if (neg) { rx = -rx; ry = -ry; rz = -rz; }
    float xi = rx;
    float yi = ry + 64.0f;
    float zi = rz + 64.0f;
    float z0 = floorf(zi), y0 = floorf(yi), x0 = floorf(xi);
    float tz = zi - z0, ty = yi - y0, tx = xi - x0;
    int z0i = (int)z0, y0i = (int)y0, x0i = (int)x0;
    float ar = 0.f, ai = 0.f;
    for (int dz = 0; dz < 2; ++dz) {
        float wz = dz ? tz : 1.0f - tz;
        int zc = z0i + dz;
        bool vz = (zc >= 0) && (zc < D);
        int zx = min(max(zc, 0), D-1);
        for (int dy = 0; dy < 2; ++dy) {
            float wy = dy ? ty : 1.0f - ty;
            int yc = y0i + dy;
            bool vy = (yc >= 0) && (yc < D);
            int yx = min(max(yc, 0), D-1);
            for (int dx = 0; dx < 2; ++dx) {
                float wx = dx ? tx : 1.0f - tx;
                int xc = x0i + dx;
                bool vx = (xc >= 0) && (xc < W);
                int xx = min(max(xc, 0), W-1);
                float wt = (vz && vy && vx) ? wz*wy*wx : 0.0f;
                float2 v = vol[zx * SLAB + yx * W + xx];
                ar = fmaf(wt, v.x, ar);
                ai = fmaf(wt, v.y, ai);
            }
        }
    }
    if (neg) ai = -ai;
    int yy = h - 64;
    if (w*w + yy*yy > 4096) { ar = 0.f; ai = 0.f; }
    projs[idx] = make_float2(ar, ai);
}

// ---------------- fused correlate + irfft2(window) + top2 ----------------
// One block (256 thr) per (b,k). All fftshift/ifftshift folded into twiddle
// index offsets. Only the 65x65 shift window (|s|<=32) is ever computed.

__global__ __launch_bounds__(256) void corr_kernel(const float2* __restrict__ parts,
                                                   const float* __restrict__ ctf,
                                                   const float2* __restrict__ projs,
                                                   float* __restrict__ outv) {
    __shared__ float2 Pbuf[D][CHUNK];     // prod (shifted layout), one x-chunk
    __shared__ float2 Gbuf[W][CHUNK];     // column-iDFT output (needed rows only)
    __shared__ float  corrs[W][W];        // accumulated windowed correlation
    __shared__ float2 tw[D];              // e^{+2*pi*i*n/128}
    __shared__ float  redv[8];
    __shared__ int    redi[8];

    int bk = blockIdx.x;
    int b = bk / NK;
    int k = bk % NK;
    int tid = threadIdx.x;

    if (tid < D) {
        float s, c;
        sincosf(TWO_PI * (float)tid / (float)D, &s, &c);
        tw[tid] = make_float2(c, s);
    }
    for (int i = tid; i < W*W; i += 256) ((float*)corrs)[i] = 0.0f;
    __syncthreads();

    const float2* Pp = parts + b * SLAB;
    const float*  Cp = ctf   + b * SLAB;
    const float2* Jp = projs + k * SLAB;
    const float inv_d = 1.0f / (float)D;

    for (int c0 = 0; c0 < W; c0 += CHUNK) {
        // ---- build P[m][x] = parts_rfft * conj(ctf * projs), shifted layout
        for (int i = tid; i < D * CHUNK; i += 256) {
            int m = i / CHUNK;
            int xl = i % CHUNK;
            int x = c0 + xl;
            float2 pr = Pp[m*W + x];
            float  cf = Cp[m*W + x];
            float2 pj = Jp[m*W + x];
            float cr = cf * pj.x;
            float ci = -cf * pj.y;        // conj
            Pbuf[m][xl] = make_float2(pr.x*cr - pr.y*ci, pr.x*ci + pr.y*cr);
        }
        __syncthreads();
        // ---- column inverse DFT restricted to shifted rows u_s in [32,96]
        for (int i = tid; i < W * CHUNK; i += 256) {
            int uu = i / CHUNK;
            int xl = i % CHUNK;
            int us = 32 + uu;
            int up = (us + 64) & (D-1);
            float ar = 0.f, ai = 0.f;
            for (int m = 0; m < D; ++m) {
                float2 p = Pbuf[m][xl];
                float2 t = tw[(m * up) & (D-1)];
                ar += p.x*t.x - p.y*t.y;
                ai += p.x*t.y + p.y*t.x;
            }
            float sg = (us & 1) ? -inv_d : inv_d;   // (-1)^u / 128
            Gbuf[uu][xl] = make_float2(ar * sg, ai * sg);
        }
        __syncthreads();
        // ---- row irfft (real part only) restricted to shifted cols v_s in [32,96]
        for (int i = tid; i < W*W; i += 256) {
            int uu = i / W;
            int v  = i % W;
            int vs = 32 + v;
            int vp = (vs + 64) & (D-1);
            float s = 0.0f;
            for (int xl = 0; xl < CHUNK; ++xl) {
                int x = c0 + xl;
                float2 X = Gbuf[uu][xl];
                if (x == 0) {
                    s += X.x;                         // DC: real part only (c2r)
                } else if (x == 64) {
                    s += (vs & 1) ? -X.x : X.x;       // Nyquist: real part only
                } else {
                    float2 t = tw[(x * vp) & (D-1)];
                    s += 2.0f * (X.x*t.x - X.y*t.y);  // Hermitian doubling
                }
            }
            corrs[uu][v] += s * inv_d;
        }
        __syncthreads();
    }

    // ---- top-2 with lax.top_k tie-breaking (lower flat index wins)
    float v1 = -INFINITY, v2 = -INFINITY;
    int i1 = 0x7fffffff, i2 = 0x7fffffff;
    for (int i = tid; i < W*W; i += 256) {
        int uu = i / W, v = i % W;
        float val = corrs[uu][v];
        int fl = (32 + uu) * D + (32 + v);   // flat index in the 128x128 array
        if (better(val, fl, v1, i1)) { v2 = v1; i2 = i1; v1 = val; i1 = fl; }
        else if (better(val, fl, v2, i2)) { v2 = val; i2 = fl; }
    }
    for (int off = 32; off > 0; off >>= 1) {
        float b1 = __shfl_down(v1, off); int j1 = __shfl_down(i1, off);
        float b2 = __shfl_down(v2, off); int j2 = __shfl_down(i2, off);
        if (better(b1, j1, v1, i1)) {
            float nv2; int ni2;
            if (better(v1, i1, b2, j2)) { nv2 = v1; ni2 = i1; } else { nv2 = b2; ni2 = j2; }
            v1 = b1; i1 = j1; v2 = nv2; i2 = ni2;
        } else {
            if (better(b1, j1, v2, i2)) { v2 = b1; i2 = j1; }
        }
    }
    int wave = tid >> 6;
    if ((tid & 63) == 0) {
        redv[wave*2]   = v1; redi[wave*2]   = i1;
        redv[wave*2+1] = v2; redi[wave*2+1] = i2;
    }
    __syncthreads();
    if (tid == 0) {
        float r1 = -INFINITY, r2 = -INFINITY;
        int q1 = 0x7fffffff, q2 = 0x7fffffff;
        for (int i = 0; i < 8; ++i) {
            float val = redv[i]; int fl = redi[i];
            if (better(val, fl, r1, q1)) { r2 = r1; q2 = q1; r1 = val; q1 = fl; }
            else if (better(val, fl, r2, q2)) { r2 = val; q2 = fl; }
        }
        int base = bk * 2;
        outv[base]     = r1;
        outv[base + 1] = r2;
        float* os = outv + NB*NK*2;   // shifts region (written as float integers)
        os[(base    )*2 + 0] = (float)(q1 / D - 64);
        os[(base    )*2 + 1] = (float)(q1 % D - 64);
        os[(base + 1)*2 + 0] = (float)(q2 / D - 64);
        os[(base + 1)*2 + 1] = (float)(q2 % D - 64);
    }
}

// ---------------- launcher ----------------

extern "C" void kernel_launch(void* const* d_in, const int* in_sizes, int n_in,
                              void* d_out, int out_size, void* d_ws, size_t ws_size,
                              hipStream_t stream) {
    const float* vol   = (const float*)d_in[0];   // (128,128,128)
    const float* parts = (const float*)d_in[1];   // (8,128,128)
    const float* ctf   = (const float*)d_in[2];   // (8,128,65)
    const float* euler = (const float*)d_in[3];   // (125,3)
    float* out = (float*)d_out;

    const int VOLC = D * SLAB;          // 1,064,960 complex
    float2* bufA   = (float2*)d_ws;                    // x-pass out; later final vol_rfft
    float2* bufB   = bufA + VOLC;                      // y-pass out
    float2* pT1    = bufB + VOLC;                      // parts x-pass (8*SLAB)
    float2* pPs    = pT1 + NB * SLAB;                  // parts_rfft shifted
    float2* projs  = pPs + NB * SLAB;                  // (125,128,65)
    float*  rot    = (float*)(projs + NK * SLAB);      // (125,9)

    // rotation matrices
    rot_kernel<<<1, 128, 0, stream>>>(euler, rot);
    // volume 3D rfft with fftshift on (z,y)
    rfft_rows<<<D*D, D, 0, stream>>>(vol, bufA, D*D);
    fft_y_shift<<<D*W, D, 0, stream>>>(bufA, bufB);
    fft_z_shift<<<SLAB, D, 0, stream>>>(bufB, bufA);
    // particles rfft2 with fftshift on y
    rfft_rows<<<NB*D, D, 0, stream>>>(parts, pT1, NB*D);
    fft_y_shift<<<NB*W, D, 0, stream>>>(pT1, pPs);
    // central-slice projections
    int nproj = NK * D * W;
    proj_kernel<<<(nproj + 255) / 256, 256, 0, stream>>>(bufA, rot, projs);
    // fused correlation + windowed top-2
    corr_kernel<<<NB * NK, 256, 0, stream>>>(pPs, ctf, projs, out);
}

// Round 2
// 357.005 us; speedup vs baseline: 1.1402x; 1.1402x over previous
//
#include <hip/hip_runtime.h>
#include <math.h>

#define D 128
#define W 65            // D/2+1
#define NK 125
#define NB 8
#define SLAB (D*W)      // 8320 elements per slab
#define NCH 16          // x-chunks in corr (x = c + 16*x1)
#define TWO_PI 6.28318530717958647692f
#define R2C 0.70710678118654752440f

// ---------------- helpers ----------------

__device__ __forceinline__ bool better(float va, int ia, float vb, int ib) {
    return (va > vb) || (va == vb && ia < ib);
}

__device__ __forceinline__ float2 cmul(float2 a, float2 b) {
    return make_float2(a.x*b.x - a.y*b.y, a.x*b.y + a.y*b.x);
}
__device__ __forceinline__ void cmac(float2& acc, float2 a, float2 b) {
    acc.x = fmaf(a.x, b.x, fmaf(-a.y, b.y, acc.x));
    acc.y = fmaf(a.x, b.y, fmaf( a.y, b.x, acc.y));
}
__device__ __forceinline__ float2 cadd(float2 a, float2 b){ return make_float2(a.x+b.x, a.y+b.y); }
__device__ __forceinline__ float2 csub(float2 a, float2 b){ return make_float2(a.x-b.x, a.y-b.y); }

// ---------------- rotation matrices ----------------

__global__ void rot_kernel(const float* __restrict__ euler, float* __restrict__ rot) {
    int k = blockIdx.x * blockDim.x + threadIdx.x;
    if (k >= NK) return;
    const float d2r = 0.017453292519943295f;
    float a = euler[k*3+0] * d2r, b = euler[k*3+1] * d2r, c = euler[k*3+2] * d2r;
    float sa, ca, sb, cb, sc, cc;
    sincosf(a, &sa, &ca);
    sincosf(b, &sb, &cb);
    sincosf(c, &sc, &cc);
    rot[k*9+0] =  ca*cb*cc - sa*sc;
    rot[k*9+1] = -ca*cb*sc - sa*cc;
    rot[k*9+2] =  ca*sb;
    rot[k*9+3] =  sa*cb*cc + ca*sc;
    rot[k*9+4] = -sa*cb*sc + ca*cc;
    rot[k*9+5] =  sa*sb;
    rot[k*9+6] = -sb*cc;
    rot[k*9+7] =  sb*sc;
    rot[k*9+8] =  cb;
}

// ---------------- forward transforms (as round-1, verified) ----------------

__global__ void rfft_rows(const float* __restrict__ in, float2* __restrict__ out, int nrows) {
    __shared__ float row[D];
    __shared__ float2 tw[D];
    int r = blockIdx.x;
    int t = threadIdx.x;
    row[t] = in[r*D + t];
    {
        float s, c;
        sincosf(-TWO_PI * (float)t / (float)D, &s, &c);
        tw[t] = make_float2(c, s);
    }
    __syncthreads();
    if (t < W) {
        float ar = 0.f, ai = 0.f;
        for (int x = 0; x < D; ++x) {
            float2 w = tw[(x * t) & (D-1)];
            float v = row[x];
            ar = fmaf(v, w.x, ar);
            ai = fmaf(v, w.y, ai);
        }
        out[r*W + t] = make_float2(ar, ai);
    }
}

__global__ void fft_y_shift(const float2* __restrict__ in, float2* __restrict__ out) {
    __shared__ float2 col[D];
    __shared__ float2 tw[D];
    int l = blockIdx.x;
    int t = threadIdx.x;
    int base = (l / W) * SLAB + (l % W);
    col[t] = in[base + t * W];
    {
        float s, c;
        sincosf(-TWO_PI * (float)t / (float)D, &s, &c);
        tw[t] = make_float2(c, s);
    }
    __syncthreads();
    int bp = (t + 64) & (D-1);
    float ar = 0.f, ai = 0.f;
    for (int y = 0; y < D; ++y) {
        float2 p = col[y];
        float2 w = tw[(y * bp) & (D-1)];
        ar += p.x*w.x - p.y*w.y;
        ai += p.x*w.y + p.y*w.x;
    }
    out[base + t * W] = make_float2(ar, ai);
}

__global__ void fft_z_shift(const float2* __restrict__ in, float2* __restrict__ out) {
    __shared__ float2 col[D];
    __shared__ float2 tw[D];
    int l = blockIdx.x;
    int t = threadIdx.x;
    col[t] = in[t * SLAB + l];
    {
        float s, c;
        sincosf(-TWO_PI * (float)t / (float)D, &s, &c);
        tw[t] = make_float2(c, s);
    }
    __syncthreads();
    int ap = (t + 64) & (D-1);
    float ar = 0.f, ai = 0.f;
    for (int z = 0; z < D; ++z) {
        float2 p = col[z];
        float2 w = tw[(z * ap) & (D-1)];
        ar += p.x*w.x - p.y*w.y;
        ai += p.x*w.y + p.y*w.x;
    }
    out[t * SLAB + l] = make_float2(ar, ai);
}

// parts y-FFT writing TRANSPOSED: QT[b][x][m] = parts_rfft_shifted[b][m][x]
__global__ void fft_y_parts_T(const float2* __restrict__ in, float2* __restrict__ outT) {
    __shared__ float2 col[D];
    __shared__ float2 tw[D];
    int l = blockIdx.x;        // b*65 + x
    int b = l / W, x = l - b * W;
    int t = threadIdx.x;
    col[t] = in[b * SLAB + t * W + x];
    {
        float s, c;
        sincosf(-TWO_PI * (float)t / (float)D, &s, &c);
        tw[t] = make_float2(c, s);
    }
    __syncthreads();
    int bp = (t + 64) & (D-1);
    float ar = 0.f, ai = 0.f;
    for (int y = 0; y < D; ++y) {
        float2 p = col[y];
        float2 w = tw[(y * bp) & (D-1)];
        ar += p.x*w.x - p.y*w.y;
        ai += p.x*w.y + p.y*w.x;
    }
    outT[l * D + t] = make_float2(ar, ai);
}

// CT[b][x][m] = ctf[b][m][x]
__global__ void ct_transpose(const float* __restrict__ ctf, float* __restrict__ CT) {
    int i = blockIdx.x * 256 + threadIdx.x;
    if (i >= NB * W * D) return;
    int m = i & (D-1);
    int t2 = i >> 7;
    int x = t2 % W;
    int b = t2 / W;
    CT[i] = ctf[b * SLAB + m * W + x];
}

// ---------------- central-slice projection (transposed write) ----------------
// PJT[k][w][h]: consecutive threads walk h -> contiguous writes.

__global__ void proj_kernel(const float2* __restrict__ vol, const float* __restrict__ rot,
                            float2* __restrict__ projT) {
    int idx = blockIdx.x * blockDim.x + threadIdx.x;
    if (idx >= NK * D * W) return;
    int h = idx & (D-1);
    int t2 = idx >> 7;
    int w = t2 % W;
    int k = t2 / W;
    float x = (float)w;
    float y = (float)(h - 64);
    const float* R = rot + k*9;
    float rx = R[0]*x + R[1]*y;
    float ry = R[3]*x + R[4]*y;
    float rz = R[6]*x + R[7]*y;
    bool neg = rx < 0.0f;
    if (neg) { rx = -rx; ry = -ry; rz = -rz; }
    float xi = rx;
    float yi = ry + 64.0f;
    float zi = rz + 64.0f;
    float z0 = floorf(zi), y0 = floorf(yi), x0 = floorf(xi);
    float tz = zi - z0, ty = yi - y0, tx = xi - x0;
    int z0i = (int)z0, y0i = (int)y0, x0i = (int)x0;
    float ar = 0.f, ai = 0.f;
    for (int dz = 0; dz < 2; ++dz) {
        float wz = dz ? tz : 1.0f - tz;
        int zc = z0i + dz;
        bool vz = (zc >= 0) && (zc < D);
        int zx = min(max(zc, 0), D-1);
        for (int dy = 0; dy < 2; ++dy) {
            float wy = dy ? ty : 1.0f - ty;
            int yc = y0i + dy;
            bool vy = (yc >= 0) && (yc < D);
            int yx = min(max(yc, 0), D-1);
            for (int dx = 0; dx < 2; ++dx) {
                float wx = dx ? tx : 1.0f - tx;
                int xc = x0i + dx;
                bool vx = (xc >= 0) && (xc < W);
                int xx = min(max(xc, 0), W-1);
                float wt = (vz && vy && vx) ? wz*wy*wx : 0.0f;
                float2 v = vol[zx * SLAB + yx * W + xx];
                ar = fmaf(wt, v.x, ar);
                ai = fmaf(wt, v.y, ai);
            }
        }
    }
    if (neg) ai = -ai;
    int yy = h - 64;
    if (w*w + yy*yy > 4096) { ar = 0.f; ai = 0.f; }
    projT[idx] = make_float2(ar, ai);
}

// ---------------- fused correlate + windowed irfft2 + top2 (two-step DFTs) ---
// One block (256 thr) per (b,k). Column transform: m = m0 + 16*m1 (8-pt reg FFT
// + 16-term twiddle stage). Row transform: x = c + 16*x1 chunks; B-stage
// amortizes x1-sum over the 8 v-classes (v&7). 65x65 accumulators in registers.

__global__ __launch_bounds__(256) void corr_kernel(const float2* __restrict__ QT,
                                                   const float*  __restrict__ CT,
                                                   const float2* __restrict__ PJT,
                                                   float* __restrict__ outv) {
    __shared__ float2 tw[D];           // e^{+2*pi*i*n/128}
    __shared__ float2 Pb[5][130];      // [col][m], padded
    __shared__ float2 Ab[5*146];       // col*146 + r*18 + m0
    __shared__ float2 Gb[5][W];        // [col][uu]
    __shared__ float2 Bb[W][8];        // [uu][s]
    __shared__ float  redv[8];
    __shared__ int    redi[8];

    int bk = blockIdx.x;
    int b = bk / NK;
    int k = bk % NK;
    int tid = threadIdx.x;
    const float inv_d = 1.0f / 128.0f;

    if (tid < D) {
        float s, c;
        sincosf(TWO_PI * (float)tid / (float)D, &s, &c);
        tw[tid] = make_float2(c, s);
    }

    int uu0, v0;
    { int i0 = tid * 17; uu0 = i0 / 65; v0 = i0 - uu0 * 65; }
    float acc[17];
    #pragma unroll
    for (int j = 0; j < 17; ++j) acc[j] = 0.0f;

    const float2* Qb = QT + b * W * D;
    const float*  Cb = CT + b * W * D;
    const float2* Jk = PJT + k * W * D;

    __syncthreads();

    for (int c = 0; c < NCH; ++c) {
        int nc = (c == 0) ? 5 : 4;
        // ---- product P[col][m] = parts_rfft * ctf * conj(projs), coalesced reads
        {
            int m = tid & (D-1), cs = tid >> 7;
            for (int col = cs; col < nc; col += 2) {
                int x = (col < 4) ? (c + 16*col) : 64;
                int off = x * D + m;
                float2 q = Qb[off];
                float cf = Cb[off];
                float2 pj = Jk[off];
                float sx = q.x * cf, sy = q.y * cf;
                Pb[col][m] = make_float2(sx*pj.x + sy*pj.y, sy*pj.x - sx*pj.y);
            }
        }
        __syncthreads();
        // ---- stage1: 8-point inverse DFT over m1 -> Ab[col][r][m0]
        if (tid < 80) {
            int m0 = tid & 15, col = tid >> 4;
            if (col < nc) {
                float2 e0 = Pb[col][m0     ], o0 = Pb[col][m0 + 16];
                float2 e1 = Pb[col][m0 + 32], o1 = Pb[col][m0 + 48];
                float2 e2 = Pb[col][m0 + 64], o2 = Pb[col][m0 + 80];
                float2 e3 = Pb[col][m0 + 96], o3 = Pb[col][m0 +112];
                // even 4-pt (w4 = +i): inputs e0,e1,e2,e3 at m1=0,2,4,6
                float2 t0 = cadd(e0, e2), t1 = csub(e0, e2);
                float2 t2 = cadd(e1, e3), t3 = csub(e1, e3);
                float2 E0 = cadd(t0, t2), E2 = csub(t0, t2);
                float2 E1 = make_float2(t1.x - t3.y, t1.y + t3.x);
                float2 E3 = make_float2(t1.x + t3.y, t1.y - t3.x);
                // odd 4-pt: o0..o3 at m1=1,3,5,7
                float2 u0 = cadd(o0, o2), u1 = csub(o0, o2);
                float2 u2 = cadd(o1, o3), u3 = csub(o1, o3);
                float2 O0 = cadd(u0, u2), O2 = csub(u0, u2);
                float2 O1 = make_float2(u0.x*0.f + u1.x - u3.y, u1.y + u3.x);
                float2 O3 = make_float2(u1.x + u3.y, u1.y - u3.x);
                // combine: X[r] = E[r&3] + w8^r * O[r&3], w8 = e^{+i pi/4}
                float2 w1o = make_float2(R2C*(O1.x - O1.y), R2C*(O1.x + O1.y));
                float2 w2o = make_float2(-O2.y, O2.x);
                float2 w3o = make_float2(R2C*(-O3.x - O3.y), R2C*(O3.x - O3.y));
                float2* A = Ab + col*146 + m0;
                A[0*18] = cadd(E0, O0);
                A[4*18] = csub(E0, O0);
                A[1*18] = cadd(E1, w1o);
                A[5*18] = csub(E1, w1o);
                A[2*18] = cadd(E2, w2o);
                A[6*18] = csub(E2, w2o);
                A[3*18] = cadd(E3, w3o);
                A[7*18] = csub(E3, w3o);
            }
        }
        __syncthreads();
        // ---- stage2: Gb[col][uu] = sum_m0 Ab[col][r][m0] * tw[m0*up], twiddle recurrence
        if (tid < W) {
            int uu = tid;
            int up = (96 + uu) & (D-1);
            int r = uu & 7;
            float2 wup = tw[up];
            float2 g0 = {0,0}, g1 = {0,0}, g2 = {0,0}, g3 = {0,0}, g4 = {0,0};
            const float4* A0 = (const float4*)(Ab + 0*146 + r*18);
            const float4* A1 = (const float4*)(Ab + 1*146 + r*18);
            const float4* A2 = (const float4*)(Ab + 2*146 + r*18);
            const float4* A3 = (const float4*)(Ab + 3*146 + r*18);
            const float4* A4 = (const float4*)(Ab + 4*146 + r*18);
            float2 tc = make_float2(1.0f, 0.0f);
            #pragma unroll
            for (int m0 = 0; m0 < 16; m0 += 2) {
                float2 tn = cmul(tc, wup);
                float4 a;
                a = A0[m0>>1]; cmac(g0, make_float2(a.x,a.y), tc); cmac(g0, make_float2(a.z,a.w), tn);
                a = A1[m0>>1]; cmac(g1, make_float2(a.x,a.y), tc); cmac(g1, make_float2(a.z,a.w), tn);
                a = A2[m0>>1]; cmac(g2, make_float2(a.x,a.y), tc); cmac(g2, make_float2(a.z,a.w), tn);
                a = A3[m0>>1]; cmac(g3, make_float2(a.x,a.y), tc); cmac(g3, make_float2(a.z,a.w), tn);
                a = A4[m0>>1]; cmac(g4, make_float2(a.x,a.y), tc); cmac(g4, make_float2(a.z,a.w), tn);
                tc = cmul(tn, wup);
            }
            float sg = (uu & 1) ? -inv_d : inv_d;
            g0.x *= sg; g0.y *= sg;
            g1.x *= sg; g1.y *= sg;
            g2.x *= sg; g2.y *= sg;
            g3.x *= sg; g3.y *= sg;
            g4.x *= sg; g4.y *= sg;
            if (c == 0) { g0.x *= 0.5f; g0.y *= 0.5f; }   // x = 0 (DC) weight
            Gb[0][uu] = g0; Gb[1][uu] = g1; Gb[2][uu] = g2; Gb[3][uu] = g3;
            Gb[4][uu] = g4;                                // x = 64 (Nyquist), used at c==0
        }
        __syncthreads();
        // ---- B stage: Bb[uu][s] = (2/128) * sum_x1 Gb[x1][uu] * w8^{x1*s}
        if (tid < W) {
            int uu = tid;
            float2 h0 = Gb[0][uu], h1 = Gb[1][uu], h2 = Gb[2][uu], h3 = Gb[3][uu];
            const float sc = 2.0f * inv_d;
            float2 p1 = make_float2(R2C*(h1.x - h1.y), R2C*(h1.x + h1.y));   // w1*h1
            float2 q1 = make_float2(R2C*(-h1.x - h1.y), R2C*(h1.x - h1.y));  // w3*h1
            float2 i1 = make_float2(-h1.y, h1.x);                            // w2*h1
            float2 i2 = make_float2(-h2.y, h2.x);                            // w2*h2
            float2 n2 = make_float2( h2.y, -h2.x);                           // w6*h2
            float2 p3 = make_float2(R2C*(h3.x - h3.y), R2C*(h3.x + h3.y));   // w1*h3
            float2 q3 = make_float2(R2C*(-h3.x - h3.y), R2C*(h3.x - h3.y));  // w3*h3
            float2 i3 = make_float2(-h3.y, h3.x);                            // w2*h3
            float2 a02 = cadd(h0, h2), s02 = csub(h0, h2);
            float2 s0 = cadd(a02, cadd(h1, h3));
            float2 s4 = csub(a02, cadd(h1, h3));
            float2 s2 = cadd(s02, csub(i1, i3));
            float2 s6 = csub(s02, csub(i1, i3));
            float2 b0i = cadd(h0, i2);
            float2 b0n = cadd(h0, n2);
            float2 s1 = cadd(b0i, cadd(p1, q3));
            float2 s5 = csub(b0i, cadd(p1, q3));
            float2 s3 = cadd(b0n, cadd(q1, p3));
            float2 s7 = csub(b0n, cadd(q1, p3));
            Bb[uu][0] = make_float2(s0.x*sc, s0.y*sc);
            Bb[uu][1] = make_float2(s1.x*sc, s1.y*sc);
            Bb[uu][2] = make_float2(s2.x*sc, s2.y*sc);
            Bb[uu][3] = make_float2(s3.x*sc, s3.y*sc);
            Bb[uu][4] = make_float2(s4.x*sc, s4.y*sc);
            Bb[uu][5] = make_float2(s5.x*sc, s5.y*sc);
            Bb[uu][6] = make_float2(s6.x*sc, s6.y*sc);
            Bb[uu][7] = make_float2(s7.x*sc, s7.y*sc);
        }
        __syncthreads();
        // ---- accumulate into registers: corr[uu][v] += Re(Bb[uu][v&7]*tw[c*vp]) (+Nyq at c==0)
        {
            int uu = uu0, v = v0;
            #pragma unroll
            for (int j = 0; j < 17; ++j) {
                int i = tid * 17 + j;
                if (i < 4225) {
                    int vp = (96 + v) & (D-1);
                    float2 Bv = Bb[uu][v & 7];
                    float2 t = tw[(c * vp) & (D-1)];
                    acc[j] = fmaf(Bv.x, t.x, fmaf(-Bv.y, t.y, acc[j]));
                    if (c == 0) {
                        float gn = Gb[4][uu].x;
                        acc[j] += (v & 1) ? -inv_d * gn : inv_d * gn;
                    }
                }
                ++v; if (v == 65) { v = 0; ++uu; }
            }
        }
        __syncthreads();  // acc reads Bb/Gb done before next chunk rewrites them
    }

    // ---- top-2 (lax.top_k tie-break: lower flat index wins)
    float v1 = -INFINITY, v2 = -INFINITY;
    int i1 = 0x7fffffff, i2 = 0x7fffffff;
    {
        int uu = uu0, v = v0;
        #pragma unroll
        for (int j = 0; j < 17; ++j) {
            int i = tid * 17 + j;
            if (i < 4225) {
                float val = acc[j];
                int fl = (32 + uu) * D + (32 + v);
                if (better(val, fl, v1, i1)) { v2 = v1; i2 = i1; v1 = val; i1 = fl; }
                else if (better(val, fl, v2, i2)) { v2 = val; i2 = fl; }
            }
            ++v; if (v == 65) { v = 0; ++uu; }
        }
    }
    for (int off = 32; off > 0; off >>= 1) {
        float b1 = __shfl_down(v1, off); int j1 = __shfl_down(i1, off);
        float b2 = __shfl_down(v2, off); int j2 = __shfl_down(i2, off);
        if (better(b1, j1, v1, i1)) {
            float nv2; int ni2;
            if (better(v1, i1, b2, j2)) { nv2 = v1; ni2 = i1; } else { nv2 = b2; ni2 = j2; }
            v1 = b1; i1 = j1; v2 = nv2; i2 = ni2;
        } else {
            if (better(b1, j1, v2, i2)) { v2 = b1; i2 = j1; }
        }
    }
    int wave = tid >> 6;
    if ((tid & 63) == 0) {
        redv[wave*2]   = v1; redi[wave*2]   = i1;
        redv[wave*2+1] = v2; redi[wave*2+1] = i2;
    }
    __syncthreads();
    if (tid == 0) {
        float r1 = -INFINITY, r2 = -INFINITY;
        int q1 = 0x7fffffff, q2 = 0x7fffffff;
        for (int i = 0; i < 8; ++i) {
            float val = redv[i]; int fl = redi[i];
            if (better(val, fl, r1, q1)) { r2 = r1; q2 = q1; r1 = val; q1 = fl; }
            else if (better(val, fl, r2, q2)) { r2 = val; q2 = fl; }
        }
        int base = bk * 2;
        outv[base]     = r1;
        outv[base + 1] = r2;
        float* os = outv + NB*NK*2;
        os[(base    )*2 + 0] = (float)(q1 / D - 64);
        os[(base    )*2 + 1] = (float)(q1 % D - 64);
        os[(base + 1)*2 + 0] = (float)(q2 / D - 64);
        os[(base + 1)*2 + 1] = (float)(q2 % D - 64);
    }
}

// ---------------- launcher ----------------

extern "C" void kernel_launch(void* const* d_in, const int* in_sizes, int n_in,
                              void* d_out, int out_size, void* d_ws, size_t ws_size,
                              hipStream_t stream) {
    const float* vol   = (const float*)d_in[0];   // (128,128,128)
    const float* parts = (const float*)d_in[1];   // (8,128,128)
    const float* ctf   = (const float*)d_in[2];   // (8,128,65)
    const float* euler = (const float*)d_in[3];   // (125,3)
    float* out = (float*)d_out;

    const int VOLC = D * SLAB;
    float2* bufA   = (float2*)d_ws;                    // vol x-pass out; later final vol_rfft
    float2* bufB   = bufA + VOLC;                      // vol y-pass out
    float2* pT1    = bufB + VOLC;                      // parts x-pass (8*SLAB)
    float2* QT     = pT1 + NB * SLAB;                  // parts_rfft shifted, TRANSPOSED [b][x][m]
    float2* PJT    = QT + NB * W * D;                  // projs TRANSPOSED [k][w][h]
    float*  CT     = (float*)(PJT + NK * W * D);       // ctf TRANSPOSED [b][x][m]
    float*  rot    = CT + NB * W * D;                  // (125,9)

    rot_kernel<<<1, 128, 0, stream>>>(euler, rot);
    // volume 3D rfft with fftshift on (z,y)
    rfft_rows<<<D*D, D, 0, stream>>>(vol, bufA, D*D);
    fft_y_shift<<<D*W, D, 0, stream>>>(bufA, bufB);
    fft_z_shift<<<SLAB, D, 0, stream>>>(bufB, bufA);
    // particles rfft2 with fftshift on y -> transposed QT
    rfft_rows<<<NB*D, D, 0, stream>>>(parts, pT1, NB*D);
    fft_y_parts_T<<<NB*W, D, 0, stream>>>(pT1, QT);
    // ctf transpose
    ct_transpose<<<(NB*W*D + 255)/256, 256, 0, stream>>>(ctf, CT);
    // central-slice projections (transposed write)
    int nproj = NK * D * W;
    proj_kernel<<<(nproj + 255) / 256, 256, 0, stream>>>(bufA, rot, PJT);
    // fused correlation + windowed top-2
    corr_kernel<<<NB * NK, 256, 0, stream>>>(QT, CT, PJT, out);
}

// Round 3
// 172.960 us; speedup vs baseline: 2.3534x; 2.0641x over previous
//
#include <hip/hip_runtime.h>
#include <math.h>

#define D 128
#define W 65            // D/2+1
#define NK 125
#define NB 8
#define SLAB (D*W)      // 8320 elements per slab
#define TWO_PI 6.28318530717958647692f
#define R2C 0.70710678118654752440f
#define LSTR 147        // fft128 LDS line stride (float2)

// ---------------- helpers ----------------

__device__ __forceinline__ bool better(float va, int ia, float vb, int ib) {
    return (va > vb) || (va == vb && ia < ib);
}
__device__ __forceinline__ float2 cmul(float2 a, float2 b) {
    return make_float2(a.x*b.x - a.y*b.y, a.x*b.y + a.y*b.x);
}
__device__ __forceinline__ void cmac(float2& acc, float2 a, float2 b) {
    acc.x = fmaf(a.x, b.x, fmaf(-a.y, b.y, acc.x));
    acc.y = fmaf(a.x, b.y, fmaf( a.y, b.x, acc.y));
}
__device__ __forceinline__ float2 cadd(float2 a, float2 b){ return make_float2(a.x+b.x, a.y+b.y); }
__device__ __forceinline__ float2 csub(float2 a, float2 b){ return make_float2(a.x-b.x, a.y-b.y); }

// forward 8-pt FFT: a[r] = sum_j x[j] e^{-2pi i j r/8}
__device__ __forceinline__ void fft8_fwd(const float2* x, float2* a) {
    float2 e0 = x[0], o0 = x[1], e1 = x[2], o1 = x[3];
    float2 e2 = x[4], o2 = x[5], e3 = x[6], o3 = x[7];
    float2 t0 = cadd(e0, e2), t1 = csub(e0, e2);
    float2 t2 = cadd(e1, e3), t3 = csub(e1, e3);
    float2 E0 = cadd(t0, t2), E2 = csub(t0, t2);
    float2 E1 = make_float2(t1.x + t3.y, t1.y - t3.x);   // t1 - i t3
    float2 E3 = make_float2(t1.x - t3.y, t1.y + t3.x);   // t1 + i t3
    float2 u0 = cadd(o0, o2), u1 = csub(o0, o2);
    float2 u2 = cadd(o1, o3), u3 = csub(o1, o3);
    float2 O0 = cadd(u0, u2), O2 = csub(u0, u2);
    float2 O1 = make_float2(u1.x + u3.y, u1.y - u3.x);
    float2 O3 = make_float2(u1.x - u3.y, u1.y + u3.x);
    float2 w1 = make_float2(R2C*(O1.x + O1.y), R2C*(O1.y - O1.x));   // e^{-i pi/4} O1
    float2 w2 = make_float2(O2.y, -O2.x);                            // -i O2
    float2 w3 = make_float2(R2C*(O3.y - O3.x), -R2C*(O3.x + O3.y));  // e^{-3i pi/4} O3
    a[0] = cadd(E0, O0); a[4] = csub(E0, O0);
    a[1] = cadd(E1, w1); a[5] = csub(E1, w1);
    a[2] = cadd(E2, w2); a[6] = csub(E2, w2);
    a[3] = cadd(E3, w3); a[7] = csub(E3, w3);
}

// ---------------- rotation matrices ----------------

__global__ void rot_kernel(const float* __restrict__ euler, float* __restrict__ rot) {
    int k = blockIdx.x * blockDim.x + threadIdx.x;
    if (k >= NK) return;
    const float d2r = 0.017453292519943295f;
    float a = euler[k*3+0] * d2r, b = euler[k*3+1] * d2r, c = euler[k*3+2] * d2r;
    float sa, ca, sb, cb, sc, cc;
    sincosf(a, &sa, &ca);
    sincosf(b, &sb, &cb);
    sincosf(c, &sc, &cc);
    rot[k*9+0] =  ca*cb*cc - sa*sc;
    rot[k*9+1] = -ca*cb*sc - sa*cc;
    rot[k*9+2] =  ca*sb;
    rot[k*9+3] =  sa*cb*cc + ca*sc;
    rot[k*9+4] = -sa*cb*sc + ca*cc;
    rot[k*9+5] =  sa*sb;
    rot[k*9+6] = -sb*cc;
    rot[k*9+7] =  sb*sc;
    rot[k*9+8] =  cb;
}

// ---------------- batched 128-pt FFT: 16 threads/line, 16 lines/block -------
// MODE 0: real rows (float in, contiguous), no shift, write k<=64 to out[l*65+k]
// MODE 1: complex, base=(l/65)*SLAB + l%65, stride 65, shift-folded, out same layout
// MODE 2: complex, base=l, stride SLAB, shift-folded, out same layout
// MODE 3: like 1 but transposed contiguous write out[l*128 + slot]

template<int MODE>
__global__ __launch_bounds__(256) void fft128_kernel(const float* __restrict__ inf,
                                                     const float2* __restrict__ inc,
                                                     float2* __restrict__ out,
                                                     int nlines) {
    __shared__ float2 Af[16 * LSTR];
    __shared__ float2 twf[128];
    int tid = threadIdx.x;
    int line, t;
    if (MODE == 0) { line = tid >> 4; t = tid & 15; }
    else           { line = tid & 15; t = tid >> 4; }
    int l = blockIdx.x * 16 + line;
    bool live = (l < nlines);

    if (tid < 128) {
        float s, c;
        sincosf(-TWO_PI * (float)tid / 128.0f, &s, &c);
        twf[tid] = make_float2(c, s);
    }

    int base = 0, stride = 1;
    if (MODE == 1 || MODE == 3) { base = (l / W) * SLAB + (l % W); stride = W; }
    else if (MODE == 2) { base = l; stride = SLAB; }

    float2 x[8];
    if (live) {
        if (MODE == 0) {
            const float* r = inf + (size_t)l * D;
            #pragma unroll
            for (int j = 0; j < 8; ++j) x[j] = make_float2(r[t + 16*j], 0.0f);
        } else {
            #pragma unroll
            for (int j = 0; j < 8; ++j) x[j] = inc[base + (t + 16*j) * stride];
        }
    } else {
        #pragma unroll
        for (int j = 0; j < 8; ++j) x[j] = make_float2(0.f, 0.f);
    }
    float2 a[8];
    fft8_fwd(x, a);
    {
        float2* Al = Af + line * LSTR + t * 9;
        #pragma unroll
        for (int r = 0; r < 8; ++r) Al[r] = a[r];
    }
    __syncthreads();
    if (live) {
        const float2* Ar = Af + line * LSTR;
        #pragma unroll
        for (int s = 0; s < 8; ++s) {
            int slot = t + 16 * s;
            int k = (MODE == 0) ? slot : (slot ^ 64);
            if (MODE == 0 && slot > 64) continue;
            int r = slot & 7;
            float2 acc = make_float2(0.f, 0.f);
            int idx = 0;
            #pragma unroll
            for (int n0 = 0; n0 < 16; ++n0) {
                cmac(acc, Ar[n0 * 9 + r], twf[idx]);
                idx = (idx + k) & 127;
            }
            if (MODE == 0)      out[(size_t)l * W + slot] = acc;
            else if (MODE == 3) out[(size_t)l * D + slot] = acc;
            else                out[base + slot * stride] = acc;
        }
    }
}

// CT[b][x][m] = ctf[b][m][x]
__global__ void ct_transpose(const float* __restrict__ ctf, float* __restrict__ CT) {
    int i = blockIdx.x * 256 + threadIdx.x;
    if (i >= NB * W * D) return;
    int m = i & (D-1);
    int t2 = i >> 7;
    int x = t2 % W;
    int b = t2 / W;
    CT[i] = ctf[b * SLAB + m * W + x];
}

// ---------------- central-slice projection (transposed write) ----------------

__global__ void proj_kernel(const float2* __restrict__ vol, const float* __restrict__ rot,
                            float2* __restrict__ projT) {
    int idx = blockIdx.x * blockDim.x + threadIdx.x;
    if (idx >= NK * D * W) return;
    int h = idx & (D-1);
    int t2 = idx >> 7;
    int w = t2 % W;
    int k = t2 / W;
    float x = (float)w;
    float y = (float)(h - 64);
    const float* R = rot + k*9;
    float rx = R[0]*x + R[1]*y;
    float ry = R[3]*x + R[4]*y;
    float rz = R[6]*x + R[7]*y;
    bool neg = rx < 0.0f;
    if (neg) { rx = -rx; ry = -ry; rz = -rz; }
    float xi = rx;
    float yi = ry + 64.0f;
    float zi = rz + 64.0f;
    float z0 = floorf(zi), y0 = floorf(yi), x0 = floorf(xi);
    float tz = zi - z0, ty = yi - y0, tx = xi - x0;
    int z0i = (int)z0, y0i = (int)y0, x0i = (int)x0;
    float ar = 0.f, ai = 0.f;
    for (int dz = 0; dz < 2; ++dz) {
        float wz = dz ? tz : 1.0f - tz;
        int zc = z0i + dz;
        bool vz = (zc >= 0) && (zc < D);
        int zx = min(max(zc, 0), D-1);
        for (int dy = 0; dy < 2; ++dy) {
            float wy = dy ? ty : 1.0f - ty;
            int yc = y0i + dy;
            bool vy = (yc >= 0) && (yc < D);
            int yx = min(max(yc, 0), D-1);
            for (int dx = 0; dx < 2; ++dx) {
                float wx = dx ? tx : 1.0f - tx;
                int xc = x0i + dx;
                bool vx = (xc >= 0) && (xc < W);
                int xx = min(max(xc, 0), W-1);
                float wt = (vz && vy && vx) ? wz*wy*wx : 0.0f;
                float2 v = vol[zx * SLAB + yx * W + xx];
                ar = fmaf(wt, v.x, ar);
                ai = fmaf(wt, v.y, ai);
            }
        }
    }
    if (neg) ai = -ai;
    int yy = h - 64;
    if (w*w + yy*yy > 4096) { ar = 0.f; ai = 0.f; }
    projT[idx] = make_float2(ar, ai);
}

// ---------------- fused correlate + windowed irfft2 + top2 ----------------
// One block per (b,k). 4 iterations x 16 columns (+Nyquist in iter 0); every
// stage uses all 256 threads. 65x65 accumulators live in registers (17/thread).

__global__ __launch_bounds__(256, 3) void corr_kernel(const float2* __restrict__ QT,
                                                      const float*  __restrict__ CT,
                                                      const float2* __restrict__ PJT,
                                                      float* __restrict__ outv) {
    __shared__ float2 tw[128];          // e^{+2 pi i n/128}
    __shared__ float2 Ab[17*144];       // [l][r][m0]: l*144 + r*18 + m0
    __shared__ float2 Gb[17][66];       // [l][uu]
    __shared__ float2 Ubuf[17*131];     // union: Pb[l][m] (l*131+m) / Bb[(uu*4+q)*8+s]
    __shared__ float  redv[8];
    __shared__ int    redi[8];

    int bk = blockIdx.x;
    int b = bk / NK;
    int k = bk - b * NK;
    int tid = threadIdx.x;
    const float inv_d = 1.0f / 128.0f;

    if (tid < 128) {
        float s, c;
        sincosf(TWO_PI * (float)tid / 128.0f, &s, &c);
        tw[tid] = make_float2(c, s);
    }

    int uu0, v0;
    { int i0 = tid * 17; uu0 = i0 / 65; v0 = i0 - uu0 * 65; }
    float acc[17];
    #pragma unroll
    for (int j = 0; j < 17; ++j) acc[j] = 0.0f;

    const float2* Qb = QT + b * (W * D);
    const float*  Cb = CT + b * (W * D);
    const float2* Jk = PJT + k * (W * D);

    __syncthreads();

    for (int cg = 0; cg < 4; ++cg) {
        int ncol = (cg == 0) ? 17 : 16;
        // ---- P stage: product, coalesced reads
        for (int i = tid; i < ncol * 128; i += 256) {
            int l = i >> 7, m = i & 127;
            int x = (l < 16) ? (4*cg + (l >> 2) + 16 * (l & 3)) : 64;
            int off = x * 128 + m;
            float2 q = Qb[off];
            float cf = Cb[off];
            float2 pj = Jk[off];
            float sx = q.x * cf, sy = q.y * cf;
            Ubuf[l * 131 + m] = make_float2(sx*pj.x + sy*pj.y, sy*pj.x - sx*pj.y);
        }
        __syncthreads();
        // ---- stage1: inverse 8-pt DFT over m1 -> Ab[l][r][m0]
        for (int i = tid; i < ncol * 16; i += 256) {
            int l = i >> 4, m0 = i & 15;
            const float2* P = Ubuf + l * 131 + m0;
            float2 e0 = P[0],  o0 = P[16];
            float2 e1 = P[32], o1 = P[48];
            float2 e2 = P[64], o2 = P[80];
            float2 e3 = P[96], o3 = P[112];
            float2 t0 = cadd(e0, e2), t1 = csub(e0, e2);
            float2 t2 = cadd(e1, e3), t3 = csub(e1, e3);
            float2 E0 = cadd(t0, t2), E2 = csub(t0, t2);
            float2 E1 = make_float2(t1.x - t3.y, t1.y + t3.x);
            float2 E3 = make_float2(t1.x + t3.y, t1.y - t3.x);
            float2 u0 = cadd(o0, o2), u1 = csub(o0, o2);
            float2 u2 = cadd(o1, o3), u3 = csub(o1, o3);
            float2 O0 = cadd(u0, u2), O2 = csub(u0, u2);
            float2 O1 = make_float2(u1.x - u3.y, u1.y + u3.x);
            float2 O3 = make_float2(u1.x + u3.y, u1.y - u3.x);
            float2 w1o = make_float2(R2C*(O1.x - O1.y), R2C*(O1.x + O1.y));
            float2 w2o = make_float2(-O2.y, O2.x);
            float2 w3o = make_float2(R2C*(-O3.x - O3.y), R2C*(O3.x - O3.y));
            float2* A = Ab + l * 144 + m0;
            A[0*18] = cadd(E0, O0);
            A[4*18] = csub(E0, O0);
            A[1*18] = cadd(E1, w1o);
            A[5*18] = csub(E1, w1o);
            A[2*18] = cadd(E2, w2o);
            A[6*18] = csub(E2, w2o);
            A[3*18] = cadd(E3, w3o);
            A[7*18] = csub(E3, w3o);
        }
        __syncthreads();
        // ---- stage2: Gb[l][uu] = sg * sum_m0 Ab[l][r][m0]*tw[m0*up]
        for (int i = tid; i < 65 * ncol; i += 256) {
            int l = i / 65, uu = i - l * 65;
            int up = (96 + uu) & 127;
            int r = uu & 7;
            const float4* Ar = (const float4*)(Ab + l * 144 + r * 18);
            float2 g = make_float2(0.f, 0.f);
            int idx = 0;
            #pragma unroll
            for (int j = 0; j < 8; ++j) {
                float4 av = Ar[j];
                float2 tA = tw[idx]; idx = (idx + up) & 127;
                float2 tB = tw[idx]; idx = (idx + up) & 127;
                cmac(g, make_float2(av.x, av.y), tA);
                cmac(g, make_float2(av.z, av.w), tB);
            }
            float sg = (uu & 1) ? -inv_d : inv_d;
            g.x *= sg; g.y *= sg;
            if (cg == 0 && l == 0) { g.x *= 0.5f; g.y *= 0.5f; }
            Gb[l][uu] = g;
        }
        __syncthreads();
        // ---- B stage: Bb[uu][q][s] = (2/128) sum_x1 Gb[q*4+x1][uu] w8^{x1 s}
        for (int i = tid; i < 65 * 4; i += 256) {
            int uu = i >> 2, q = i & 3;
            float2 h0 = Gb[q*4 + 0][uu];
            float2 h1 = Gb[q*4 + 1][uu];
            float2 h2 = Gb[q*4 + 2][uu];
            float2 h3 = Gb[q*4 + 3][uu];
            const float sc = 2.0f * inv_d;
            float2 p1 = make_float2(R2C*(h1.x - h1.y), R2C*(h1.x + h1.y));
            float2 q1 = make_float2(R2C*(-h1.x - h1.y), R2C*(h1.x - h1.y));
            float2 i1 = make_float2(-h1.y, h1.x);
            float2 i2 = make_float2(-h2.y, h2.x);
            float2 n2 = make_float2( h2.y, -h2.x);
            float2 p3 = make_float2(R2C*(h3.x - h3.y), R2C*(h3.x + h3.y));
            float2 q3 = make_float2(R2C*(-h3.x - h3.y), R2C*(h3.x - h3.y));
            float2 i3 = make_float2(-h3.y, h3.x);
            float2 a02 = cadd(h0, h2), s02 = csub(h0, h2);
            float2 s0 = cadd(a02, cadd(h1, h3));
            float2 s4 = csub(a02, cadd(h1, h3));
            float2 s2 = cadd(s02, csub(i1, i3));
            float2 s6 = csub(s02, csub(i1, i3));
            float2 b0i = cadd(h0, i2);
            float2 b0n = cadd(h0, n2);
            float2 s1 = cadd(b0i, cadd(p1, q3));
            float2 s5 = csub(b0i, cadd(p1, q3));
            float2 s3 = cadd(b0n, cadd(q1, p3));
            float2 s7 = csub(b0n, cadd(q1, p3));
            float2* Bp = Ubuf + (uu * 4 + q) * 8;
            Bp[0] = make_float2(s0.x*sc, s0.y*sc);
            Bp[1] = make_float2(s1.x*sc, s1.y*sc);
            Bp[2] = make_float2(s2.x*sc, s2.y*sc);
            Bp[3] = make_float2(s3.x*sc, s3.y*sc);
            Bp[4] = make_float2(s4.x*sc, s4.y*sc);
            Bp[5] = make_float2(s5.x*sc, s5.y*sc);
            Bp[6] = make_float2(s6.x*sc, s6.y*sc);
            Bp[7] = make_float2(s7.x*sc, s7.y*sc);
        }
        __syncthreads();
        // ---- accumulate: acc[uu][v] += sum_q Re(Bb[uu][q][v&7]*tw[cc*vp]) (+Nyq at cg==0)
        {
            int uu = uu0, v = v0;
            int cc0 = 4 * cg;
            #pragma unroll
            for (int j = 0; j < 17; ++j) {
                int i = tid * 17 + j;
                if (i < 4225) {
                    int vp = (96 + v) & 127;
                    int s = v & 7;
                    const float2* Bp = Ubuf + (uu * 4) * 8 + s;
                    float2 B0 = Bp[0], B1 = Bp[8], B2 = Bp[16], B3 = Bp[24];
                    float2 t0 = tw[( cc0      * vp) & 127];
                    float2 t1 = tw[((cc0 + 1) * vp) & 127];
                    float2 t2 = tw[((cc0 + 2) * vp) & 127];
                    float2 t3 = tw[((cc0 + 3) * vp) & 127];
                    float av = acc[j];
                    av = fmaf(B0.x, t0.x, fmaf(-B0.y, t0.y, av));
                    av = fmaf(B1.x, t1.x, fmaf(-B1.y, t1.y, av));
                    av = fmaf(B2.x, t2.x, fmaf(-B2.y, t2.y, av));
                    av = fmaf(B3.x, t3.x, fmaf(-B3.y, t3.y, av));
                    if (cg == 0) {
                        float gn = Gb[16][uu].x;
                        av += (v & 1) ? -inv_d * gn : inv_d * gn;
                    }
                    acc[j] = av;
                }
                ++v; if (v == 65) { v = 0; ++uu; }
            }
        }
        __syncthreads();   // before next iteration rewrites Ubuf/Gb
    }

    // ---- top-2 (lax.top_k tie-break: lower flat index wins)
    float v1 = -INFINITY, v2 = -INFINITY;
    int i1 = 0x7fffffff, i2 = 0x7fffffff;
    {
        int uu = uu0, v = v0;
        #pragma unroll
        for (int j = 0; j < 17; ++j) {
            int i = tid * 17 + j;
            if (i < 4225) {
                float val = acc[j];
                int fl = (32 + uu) * D + (32 + v);
                if (better(val, fl, v1, i1)) { v2 = v1; i2 = i1; v1 = val; i1 = fl; }
                else if (better(val, fl, v2, i2)) { v2 = val; i2 = fl; }
            }
            ++v; if (v == 65) { v = 0; ++uu; }
        }
    }
    for (int off = 32; off > 0; off >>= 1) {
        float b1 = __shfl_down(v1, off); int j1 = __shfl_down(i1, off);
        float b2 = __shfl_down(v2, off); int j2 = __shfl_down(i2, off);
        if (better(b1, j1, v1, i1)) {
            float nv2; int ni2;
            if (better(v1, i1, b2, j2)) { nv2 = v1; ni2 = i1; } else { nv2 = b2; ni2 = j2; }
            v1 = b1; i1 = j1; v2 = nv2; i2 = ni2;
        } else {
            if (better(b1, j1, v2, i2)) { v2 = b1; i2 = j1; }
        }
    }
    int wave = tid >> 6;
    if ((tid & 63) == 0) {
        redv[wave*2]   = v1; redi[wave*2]   = i1;
        redv[wave*2+1] = v2; redi[wave*2+1] = i2;
    }
    __syncthreads();
    if (tid == 0) {
        float r1 = -INFINITY, r2 = -INFINITY;
        int q1 = 0x7fffffff, q2 = 0x7fffffff;
        for (int i = 0; i < 8; ++i) {
            float val = redv[i]; int fl = redi[i];
            if (better(val, fl, r1, q1)) { r2 = r1; q2 = q1; r1 = val; q1 = fl; }
            else if (better(val, fl, r2, q2)) { r2 = val; q2 = fl; }
        }
        int base = bk * 2;
        outv[base]     = r1;
        outv[base + 1] = r2;
        float* os = outv + NB*NK*2;
        os[(base    )*2 + 0] = (float)(q1 / D - 64);
        os[(base    )*2 + 1] = (float)(q1 % D - 64);
        os[(base + 1)*2 + 0] = (float)(q2 / D - 64);
        os[(base + 1)*2 + 1] = (float)(q2 % D - 64);
    }
}

// ---------------- launcher ----------------

extern "C" void kernel_launch(void* const* d_in, const int* in_sizes, int n_in,
                              void* d_out, int out_size, void* d_ws, size_t ws_size,
                              hipStream_t stream) {
    const float* vol   = (const float*)d_in[0];   // (128,128,128)
    const float* parts = (const float*)d_in[1];   // (8,128,128)
    const float* ctf   = (const float*)d_in[2];   // (8,128,65)
    const float* euler = (const float*)d_in[3];   // (125,3)
    float* out = (float*)d_out;

    const int VOLC = D * SLAB;
    float2* bufA   = (float2*)d_ws;                    // vol x-pass out; later final vol_rfft
    float2* bufB   = bufA + VOLC;                      // vol y-pass out
    float2* pT1    = bufB + VOLC;                      // parts x-pass (8*SLAB)
    float2* QT     = pT1 + NB * SLAB;                  // parts_rfft shifted, transposed [b][x][m]
    float2* PJT    = QT + NB * W * D;                  // projs transposed [k][w][h]
    float*  CT     = (float*)(PJT + NK * W * D);       // ctf transposed [b][x][m]
    float*  rot    = CT + NB * W * D;                  // (125,9)

    rot_kernel<<<1, 128, 0, stream>>>(euler, rot);
    // volume 3D rfft with fftshift on (z,y)
    fft128_kernel<0><<<1024, 256, 0, stream>>>(vol, nullptr, bufA, D*D);
    fft128_kernel<1><<<520, 256, 0, stream>>>(nullptr, bufA, bufB, D*W);
    fft128_kernel<2><<<520, 256, 0, stream>>>(nullptr, bufB, bufA, SLAB);
    // particles rfft2 with fftshift on y -> transposed QT
    fft128_kernel<0><<<64, 256, 0, stream>>>(parts, nullptr, pT1, NB*D);
    fft128_kernel<3><<<33, 256, 0, stream>>>(nullptr, pT1, QT, NB*W);
    // ctf transpose
    ct_transpose<<<(NB*W*D + 255)/256, 256, 0, stream>>>(ctf, CT);
    // central-slice projections (transposed write)
    proj_kernel<<<(NK*D*W + 255) / 256, 256, 0, stream>>>(bufA, rot, PJT);
    // fused correlation + windowed top-2
    corr_kernel<<<NB * NK, 256, 0, stream>>>(QT, CT, PJT, out);
}

// Round 4
// 94.442 us; speedup vs baseline: 4.3100x; 1.8314x over previous
//
#include <hip/hip_runtime.h>
#include <math.h>

#define D 128
#define W 65            // D/2+1
#define NK 125
#define NB 8
#define SLAB (D*W)      // 8320 elements per slab
#define TWO_PI 6.28318530717958647692f
#define R2C 0.70710678118654752440f
#define LSTR 147        // fft128 LDS line stride (float2)

// ---------------- helpers ----------------

__device__ __forceinline__ bool better(float va, int ia, float vb, int ib) {
    return (va > vb) || (va == vb && ia < ib);
}
__device__ __forceinline__ float2 cmul(float2 a, float2 b) {
    return make_float2(a.x*b.x - a.y*b.y, a.x*b.y + a.y*b.x);
}
__device__ __forceinline__ void cmac(float2& acc, float2 a, float2 b) {
    acc.x = fmaf(a.x, b.x, fmaf(-a.y, b.y, acc.x));
    acc.y = fmaf(a.x, b.y, fmaf( a.y, b.x, acc.y));
}
__device__ __forceinline__ float2 cadd(float2 a, float2 b){ return make_float2(a.x+b.x, a.y+b.y); }
__device__ __forceinline__ float2 csub(float2 a, float2 b){ return make_float2(a.x-b.x, a.y-b.y); }

// forward 8-pt FFT: a[r] = sum_j x[j] e^{-2pi i j r/8}
__device__ __forceinline__ void fft8_fwd(const float2* x, float2* a) {
    float2 e0 = x[0], o0 = x[1], e1 = x[2], o1 = x[3];
    float2 e2 = x[4], o2 = x[5], e3 = x[6], o3 = x[7];
    float2 t0 = cadd(e0, e2), t1 = csub(e0, e2);
    float2 t2 = cadd(e1, e3), t3 = csub(e1, e3);
    float2 E0 = cadd(t0, t2), E2 = csub(t0, t2);
    float2 E1 = make_float2(t1.x + t3.y, t1.y - t3.x);
    float2 E3 = make_float2(t1.x - t3.y, t1.y + t3.x);
    float2 u0 = cadd(o0, o2), u1 = csub(o0, o2);
    float2 u2 = cadd(o1, o3), u3 = csub(o1, o3);
    float2 O0 = cadd(u0, u2), O2 = csub(u0, u2);
    float2 O1 = make_float2(u1.x + u3.y, u1.y - u3.x);
    float2 O3 = make_float2(u1.x - u3.y, u1.y + u3.x);
    float2 w1 = make_float2(R2C*(O1.x + O1.y), R2C*(O1.y - O1.x));
    float2 w2 = make_float2(O2.y, -O2.x);
    float2 w3 = make_float2(R2C*(O3.y - O3.x), -R2C*(O3.x + O3.y));
    a[0] = cadd(E0, O0); a[4] = csub(E0, O0);
    a[1] = cadd(E1, w1); a[5] = csub(E1, w1);
    a[2] = cadd(E2, w2); a[6] = csub(E2, w2);
    a[3] = cadd(E3, w3); a[7] = csub(E3, w3);
}

// ---------------- batched 128-pt FFT as device function ----------------
// MODE 0: real rows (float in, contiguous), write k<=64 to out[l*65+k]
// MODE 1: complex, base=(l/65)*SLAB+l%65, stride 65, shift-folded, same layout out
// MODE 2: complex, base=l, stride SLAB, shift-folded, same layout out
// MODE 3: like 1 but transposed contiguous write out[l*128+slot]

template<int MODE>
__device__ __forceinline__ void fft128_line(const float* __restrict__ inf,
                                            const float2* __restrict__ inc,
                                            float2* __restrict__ out,
                                            int l0, int nlines,
                                            float2* Af, float2* twf) {
    int tid = threadIdx.x;
    int line, t;
    if (MODE == 0) { line = tid >> 4; t = tid & 15; }
    else           { line = tid & 15; t = tid >> 4; }
    int l = l0 + line;
    bool live = (l < nlines);

    if (tid < 128) {
        float s, c;
        sincosf(-TWO_PI * (float)tid / 128.0f, &s, &c);
        twf[tid] = make_float2(c, s);
    }

    int base = 0, stride = 1;
    if (MODE == 1 || MODE == 3) { base = (l / W) * SLAB + (l % W); stride = W; }
    else if (MODE == 2) { base = l; stride = SLAB; }

    float2 x[8];
    if (live) {
        if (MODE == 0) {
            const float* r = inf + (size_t)l * D;
            #pragma unroll
            for (int j = 0; j < 8; ++j) x[j] = make_float2(r[t + 16*j], 0.0f);
        } else {
            #pragma unroll
            for (int j = 0; j < 8; ++j) x[j] = inc[base + (t + 16*j) * stride];
        }
    } else {
        #pragma unroll
        for (int j = 0; j < 8; ++j) x[j] = make_float2(0.f, 0.f);
    }
    float2 a[8];
    fft8_fwd(x, a);
    {
        float2* Al = Af + line * LSTR + t * 9;
        #pragma unroll
        for (int r = 0; r < 8; ++r) Al[r] = a[r];
    }
    __syncthreads();
    if (live) {
        const float2* Ar = Af + line * LSTR;
        #pragma unroll
        for (int s = 0; s < 8; ++s) {
            int slot = t + 16 * s;
            int k = (MODE == 0) ? slot : (slot ^ 64);
            if (MODE == 0 && slot > 64) continue;
            int r = slot & 7;
            float2 acc = make_float2(0.f, 0.f);
            int idx = 0;
            #pragma unroll
            for (int n0 = 0; n0 < 16; ++n0) {
                cmac(acc, Ar[n0 * 9 + r], twf[idx]);
                idx = (idx + k) & 127;
            }
            if (MODE == 0)      out[(size_t)l * W + slot] = acc;
            else if (MODE == 3) out[(size_t)l * D + slot] = acc;
            else                out[base + slot * stride] = acc;
        }
    }
}

// ---------------- merged prologue kernels ----------------

// K1: vol x-FFT (1024 blks) | parts x-FFT (64) | rot (1) | ctf transpose (260)
__global__ __launch_bounds__(256) void k1_kernel(const float* __restrict__ vol,
                                                 const float* __restrict__ parts,
                                                 const float* __restrict__ ctf,
                                                 const float* __restrict__ euler,
                                                 float2* __restrict__ bufA,
                                                 float2* __restrict__ pT1,
                                                 float* __restrict__ CT,
                                                 float* __restrict__ rot) {
    __shared__ float2 Af[16 * LSTR];
    __shared__ float2 twf[128];
    int bid = blockIdx.x;
    int tid = threadIdx.x;
    if (bid < 1024) {
        fft128_line<0>(vol, nullptr, bufA, bid * 16, D*D, Af, twf);
    } else if (bid < 1088) {
        fft128_line<0>(parts, nullptr, pT1, (bid - 1024) * 16, NB*D, Af, twf);
    } else if (bid == 1088) {
        int k = tid;
        if (k < NK) {
            const float d2r = 0.017453292519943295f;
            float a = euler[k*3+0]*d2r, b = euler[k*3+1]*d2r, c = euler[k*3+2]*d2r;
            float sa, ca, sb, cb, sc, cc;
            sincosf(a, &sa, &ca); sincosf(b, &sb, &cb); sincosf(c, &sc, &cc);
            rot[k*9+0] =  ca*cb*cc - sa*sc;
            rot[k*9+1] = -ca*cb*sc - sa*cc;
            rot[k*9+2] =  ca*sb;
            rot[k*9+3] =  sa*cb*cc + ca*sc;
            rot[k*9+4] = -sa*cb*sc + ca*cc;
            rot[k*9+5] =  sa*sb;
            rot[k*9+6] = -sb*cc;
            rot[k*9+7] =  sb*sc;
            rot[k*9+8] =  cb;
        }
    } else {
        int i = (bid - 1089) * 256 + tid;
        if (i < NB * W * D) {
            int m = i & (D-1);
            int t2 = i >> 7;
            int x = t2 % W;
            int b = t2 / W;
            CT[i] = ctf[b * SLAB + m * W + x];
        }
    }
}

// K2: vol y-FFT (520 blks) | parts y-FFT transposed (33)
__global__ __launch_bounds__(256) void k2_kernel(const float2* __restrict__ bufA,
                                                 float2* __restrict__ bufB,
                                                 const float2* __restrict__ pT1,
                                                 float2* __restrict__ QT) {
    __shared__ float2 Af[16 * LSTR];
    __shared__ float2 twf[128];
    int bid = blockIdx.x;
    if (bid < 520) fft128_line<1>(nullptr, bufA, bufB, bid * 16, D*W, Af, twf);
    else           fft128_line<3>(nullptr, pT1, QT, (bid - 520) * 16, NB*W, Af, twf);
}

// K3: vol z-FFT
__global__ __launch_bounds__(256) void k3_kernel(const float2* __restrict__ bufB,
                                                 float2* __restrict__ bufA) {
    __shared__ float2 Af[16 * LSTR];
    __shared__ float2 twf[128];
    fft128_line<2>(nullptr, bufB, bufA, blockIdx.x * 16, SLAB, Af, twf);
}

// ---------------- central-slice projection (transposed write) ----------------

__global__ void proj_kernel(const float2* __restrict__ vol, const float* __restrict__ rot,
                            float2* __restrict__ projT) {
    int idx = blockIdx.x * blockDim.x + threadIdx.x;
    if (idx >= NK * D * W) return;
    int h = idx & (D-1);
    int t2 = idx >> 7;
    int w = t2 % W;
    int k = t2 / W;
    float x = (float)w;
    float y = (float)(h - 64);
    const float* R = rot + k*9;
    float rx = R[0]*x + R[1]*y;
    float ry = R[3]*x + R[4]*y;
    float rz = R[6]*x + R[7]*y;
    bool neg = rx < 0.0f;
    if (neg) { rx = -rx; ry = -ry; rz = -rz; }
    float xi = rx;
    float yi = ry + 64.0f;
    float zi = rz + 64.0f;
    float z0 = floorf(zi), y0 = floorf(yi), x0 = floorf(xi);
    float tz = zi - z0, ty = yi - y0, tx = xi - x0;
    int z0i = (int)z0, y0i = (int)y0, x0i = (int)x0;
    float ar = 0.f, ai = 0.f;
    for (int dz = 0; dz < 2; ++dz) {
        float wz = dz ? tz : 1.0f - tz;
        int zc = z0i + dz;
        bool vz = (zc >= 0) && (zc < D);
        int zx = min(max(zc, 0), D-1);
        for (int dy = 0; dy < 2; ++dy) {
            float wy = dy ? ty : 1.0f - ty;
            int yc = y0i + dy;
            bool vy = (yc >= 0) && (yc < D);
            int yx = min(max(yc, 0), D-1);
            for (int dx = 0; dx < 2; ++dx) {
                float wx = dx ? tx : 1.0f - tx;
                int xc = x0i + dx;
                bool vx = (xc >= 0) && (xc < W);
                int xx = min(max(xc, 0), W-1);
                float wt = (vz && vy && vx) ? wz*wy*wx : 0.0f;
                float2 v = vol[zx * SLAB + yx * W + xx];
                ar = fmaf(wt, v.x, ar);
                ai = fmaf(wt, v.y, ai);
            }
        }
    }
    if (neg) ai = -ai;
    int yy = h - 64;
    if (w*w + yy*yy > 4096) { ar = 0.f; ai = 0.f; }
    projT[idx] = make_float2(ar, ai);
}

// ---------------- fused correlate + windowed irfft2 + top2 ----------------
// One block per (b,k). 4 chunks x 16 columns (+Nyquist in chunk 0).
// stage1: global product + 8pt iFFT -> Ab. stage2B: column twiddle stage +
// 4-term x1 butterfly -> BRe/BIm (SoA) + Ny. acc: register accumulation with
// twiddle recurrences; thread owns (uu=tid>>2, v=(tid&3)*16+j) -> s=j&7 static.

__global__ __launch_bounds__(256, 4) void corr_kernel(const float2* __restrict__ QT,
                                                      const float*  __restrict__ CT,
                                                      const float2* __restrict__ PJT,
                                                      float* __restrict__ outv) {
    __shared__ float2 tw[128];          // e^{+2 pi i n/128}
    __shared__ float2 Ab[17*144];       // [l][r][m0]: l*144 + r*18 + m0
    __shared__ float  BRe[8*4*67];      // [(s*4+q)*67 + uu]
    __shared__ float  BIm[8*4*67];
    __shared__ float  Ny[65];
    __shared__ float  redv[8];
    __shared__ int    redi[8];

    int bk = blockIdx.x;
    int b = bk / NK;
    int k = bk - b * NK;
    int tid = threadIdx.x;
    const float inv_d = 1.0f / 128.0f;

    if (tid < 128) {
        float s, c;
        sincosf(TWO_PI * (float)tid / 128.0f, &s, &c);
        tw[tid] = make_float2(c, s);
    }

    const float2* Qb = QT + b * (W * D);
    const float*  Cb = CT + b * (W * D);
    const float2* Jk = PJT + k * (W * D);

    int uu = tid >> 2;          // 0..63
    int vg = tid & 3;           // v = vg*16 + j
    int vp0 = 96 + vg * 16;
    float acc[16];
    #pragma unroll
    for (int j = 0; j < 16; ++j) acc[j] = 0.0f;
    float accR = 0.0f;          // rim accumulator (tid<129)
    int ur = 0, vr = 0;
    if (tid < 129) { if (tid < 65) { ur = 64; vr = tid; } else { ur = tid - 65; vr = 64; } }

    __syncthreads();

    for (int cg = 0; cg < 4; ++cg) {
        int ncol = (cg == 0) ? 17 : 16;
        // ---- stage1: fused product + inverse 8-pt DFT -> Ab[l][r][m0]
        for (int i = tid; i < ncol * 16; i += 256) {
            int l = i >> 4, m0 = i & 15;
            int x = (l < 16) ? (4*cg + (l >> 2) + 16 * (l & 3)) : 64;
            const float2* Qx = Qb + x * 128 + m0;
            const float*  Cx = Cb + x * 128 + m0;
            const float2* Jx = Jk + x * 128 + m0;
            float2 p[8];
            #pragma unroll
            for (int j = 0; j < 8; ++j) {
                float2 qv = Qx[16*j];
                float  cf = Cx[16*j];
                float2 pj = Jx[16*j];
                float sx = qv.x * cf, sy = qv.y * cf;
                p[j] = make_float2(sx*pj.x + sy*pj.y, sy*pj.x - sx*pj.y);
            }
            // inverse 8-pt DFT (w = e^{+i 2pi/8})
            float2 e0 = p[0], o0 = p[1], e1 = p[2], o1 = p[3];
            float2 e2 = p[4], o2 = p[5], e3 = p[6], o3 = p[7];
            float2 t0 = cadd(e0, e2), t1 = csub(e0, e2);
            float2 t2 = cadd(e1, e3), t3 = csub(e1, e3);
            float2 E0 = cadd(t0, t2), E2 = csub(t0, t2);
            float2 E1 = make_float2(t1.x - t3.y, t1.y + t3.x);
            float2 E3 = make_float2(t1.x + t3.y, t1.y - t3.x);
            float2 u0 = cadd(o0, o2), u1 = csub(o0, o2);
            float2 u2 = cadd(o1, o3), u3 = csub(o1, o3);
            float2 O0 = cadd(u0, u2), O2 = csub(u0, u2);
            float2 O1 = make_float2(u1.x - u3.y, u1.y + u3.x);
            float2 O3 = make_float2(u1.x + u3.y, u1.y - u3.x);
            float2 w1o = make_float2(R2C*(O1.x - O1.y), R2C*(O1.x + O1.y));
            float2 w2o = make_float2(-O2.y, O2.x);
            float2 w3o = make_float2(R2C*(-O3.x - O3.y), R2C*(O3.x - O3.y));
            float2* A = Ab + l * 144 + m0;
            A[0*18] = cadd(E0, O0);
            A[4*18] = csub(E0, O0);
            A[1*18] = cadd(E1, w1o);
            A[5*18] = csub(E1, w1o);
            A[2*18] = cadd(E2, w2o);
            A[6*18] = csub(E2, w2o);
            A[3*18] = cadd(E3, w3o);
            A[7*18] = csub(E3, w3o);
        }
        __syncthreads();
        // ---- stage2B: column twiddle stage + x1 butterfly -> BRe/BIm, Ny
        {
            int lim = (cg == 0) ? 325 : 260;
            for (int i = tid; i < lim; i += 256) {
                if (i < 260) {
                    int q = i / 65;
                    int u2 = i - q * 65;
                    int r = u2 & 7, up = (96 + u2) & 127;
                    float2 wup = tw[up];
                    const float4* A0 = (const float4*)(Ab + (4*q+0)*144 + r*18);
                    const float4* A1 = (const float4*)(Ab + (4*q+1)*144 + r*18);
                    const float4* A2 = (const float4*)(Ab + (4*q+2)*144 + r*18);
                    const float4* A3 = (const float4*)(Ab + (4*q+3)*144 + r*18);
                    float2 g0{0,0}, g1{0,0}, g2{0,0}, g3{0,0};
                    float2 tc = make_float2(1.0f, 0.0f);
                    #pragma unroll
                    for (int h = 0; h < 8; ++h) {
                        float2 tA = tc;
                        float2 tB = cmul(tA, wup);
                        tc = cmul(tB, wup);
                        float4 a;
                        a = A0[h]; cmac(g0, make_float2(a.x,a.y), tA); cmac(g0, make_float2(a.z,a.w), tB);
                        a = A1[h]; cmac(g1, make_float2(a.x,a.y), tA); cmac(g1, make_float2(a.z,a.w), tB);
                        a = A2[h]; cmac(g2, make_float2(a.x,a.y), tA); cmac(g2, make_float2(a.z,a.w), tB);
                        a = A3[h]; cmac(g3, make_float2(a.x,a.y), tA); cmac(g3, make_float2(a.z,a.w), tB);
                    }
                    float sg = (u2 & 1) ? -inv_d : inv_d;
                    g0.x *= sg; g0.y *= sg; g1.x *= sg; g1.y *= sg;
                    g2.x *= sg; g2.y *= sg; g3.x *= sg; g3.y *= sg;
                    if (cg == 0 && q == 0) { g0.x *= 0.5f; g0.y *= 0.5f; }
                    // 4-term butterfly over x1 -> s = 0..7 (w8 = e^{+i pi/4})
                    float2 h0 = g0, h1 = g1, h2 = g2, h3 = g3;
                    const float sc = 2.0f * inv_d;
                    float2 p1 = make_float2(R2C*(h1.x - h1.y), R2C*(h1.x + h1.y));
                    float2 q1 = make_float2(R2C*(-h1.x - h1.y), R2C*(h1.x - h1.y));
                    float2 i1 = make_float2(-h1.y, h1.x);
                    float2 i2 = make_float2(-h2.y, h2.x);
                    float2 n2 = make_float2( h2.y, -h2.x);
                    float2 p3 = make_float2(R2C*(h3.x - h3.y), R2C*(h3.x + h3.y));
                    float2 q3 = make_float2(R2C*(-h3.x - h3.y), R2C*(h3.x - h3.y));
                    float2 i3 = make_float2(-h3.y, h3.x);
                    float2 a02 = cadd(h0, h2), s02 = csub(h0, h2);
                    float2 s0 = cadd(a02, cadd(h1, h3));
                    float2 s4 = csub(a02, cadd(h1, h3));
                    float2 s2 = cadd(s02, csub(i1, i3));
                    float2 s6 = csub(s02, csub(i1, i3));
                    float2 b0i = cadd(h0, i2);
                    float2 b0n = cadd(h0, n2);
                    float2 s1 = cadd(b0i, cadd(p1, q3));
                    float2 s5 = csub(b0i, cadd(p1, q3));
                    float2 s3 = cadd(b0n, cadd(q1, p3));
                    float2 s7 = csub(b0n, cadd(q1, p3));
                    int wb = q * 67 + u2;
                    BRe[wb + 0*268] = s0.x*sc; BIm[wb + 0*268] = s0.y*sc;
                    BRe[wb + 1*268] = s1.x*sc; BIm[wb + 1*268] = s1.y*sc;
                    BRe[wb + 2*268] = s2.x*sc; BIm[wb + 2*268] = s2.y*sc;
                    BRe[wb + 3*268] = s3.x*sc; BIm[wb + 3*268] = s3.y*sc;
                    BRe[wb + 4*268] = s4.x*sc; BIm[wb + 4*268] = s4.y*sc;
                    BRe[wb + 5*268] = s5.x*sc; BIm[wb + 5*268] = s5.y*sc;
                    BRe[wb + 6*268] = s6.x*sc; BIm[wb + 6*268] = s6.y*sc;
                    BRe[wb + 7*268] = s7.x*sc; BIm[wb + 7*268] = s7.y*sc;
                } else {
                    int u2 = i - 260;
                    int r = u2 & 7, up = (96 + u2) & 127;
                    float2 wup = tw[up];
                    const float4* A = (const float4*)(Ab + 16*144 + r*18);
                    float re = 0.0f;
                    float2 tc = make_float2(1.0f, 0.0f);
                    #pragma unroll
                    for (int h = 0; h < 8; ++h) {
                        float2 tA = tc;
                        float2 tB = cmul(tA, wup);
                        tc = cmul(tB, wup);
                        float4 a = A[h];
                        re = fmaf(a.x, tA.x, fmaf(-a.y, tA.y, re));
                        re = fmaf(a.z, tB.x, fmaf(-a.w, tB.y, re));
                    }
                    Ny[u2] = ((u2 & 1) ? -inv_d : inv_d) * re;
                }
            }
        }
        __syncthreads();
        // ---- acc: register accumulation, twiddle recurrence per thread
        {
            float2 t0 = tw[((4*cg+0) * vp0) & 127];
            float2 t1 = tw[((4*cg+1) * vp0) & 127];
            float2 t2 = tw[((4*cg+2) * vp0) & 127];
            float2 t3 = tw[((4*cg+3) * vp0) & 127];
            float2 u0 = tw[((4*cg+0) * 8) & 127];
            float2 u1 = tw[((4*cg+1) * 8) & 127];
            float2 u2w = tw[((4*cg+2) * 8) & 127];
            float2 u3 = tw[((4*cg+3) * 8) & 127];
            float2 w0 = tw[(4*cg+0) & 127];
            float2 w1 = tw[(4*cg+1) & 127];
            float2 w2 = tw[(4*cg+2) & 127];
            float2 w3 = tw[(4*cg+3) & 127];
            float nyv = (cg == 0) ? inv_d * Ny[uu] : 0.0f;
            #pragma unroll
            for (int s = 0; s < 8; ++s) {
                int bb = s * 268 + uu;
                float br0 = BRe[bb      ], bi0 = BIm[bb      ];
                float br1 = BRe[bb +  67], bi1 = BIm[bb +  67];
                float br2 = BRe[bb + 134], bi2 = BIm[bb + 134];
                float br3 = BRe[bb + 201], bi3 = BIm[bb + 201];
                float av = acc[s];
                av = fmaf(br0, t0.x, fmaf(-bi0, t0.y, av));
                av = fmaf(br1, t1.x, fmaf(-bi1, t1.y, av));
                av = fmaf(br2, t2.x, fmaf(-bi2, t2.y, av));
                av = fmaf(br3, t3.x, fmaf(-bi3, t3.y, av));
                float2 t20 = cmul(t0, u0), t21 = cmul(t1, u1);
                float2 t22 = cmul(t2, u2w), t23 = cmul(t3, u3);
                float aw = acc[s + 8];
                aw = fmaf(br0, t20.x, fmaf(-bi0, t20.y, aw));
                aw = fmaf(br1, t21.x, fmaf(-bi1, t21.y, aw));
                aw = fmaf(br2, t22.x, fmaf(-bi2, t22.y, aw));
                aw = fmaf(br3, t23.x, fmaf(-bi3, t23.y, aw));
                if (cg == 0) {
                    float sgn = (s & 1) ? -nyv : nyv;
                    av += sgn; aw += sgn;
                }
                acc[s] = av; acc[s + 8] = aw;
                t0 = cmul(t0, w0); t1 = cmul(t1, w1);
                t2 = cmul(t2, w2); t3 = cmul(t3, w3);
            }
            if (tid < 129) {
                int sr = vr & 7, vpr = (96 + vr) & 127;
                float a = accR;
                #pragma unroll
                for (int q = 0; q < 4; ++q) {
                    float2 t = tw[((4*cg + q) * vpr) & 127];
                    int bb = (sr * 4 + q) * 67 + ur;
                    a = fmaf(BRe[bb], t.x, fmaf(-BIm[bb], t.y, a));
                }
                if (cg == 0) a += (vr & 1) ? -inv_d * Ny[ur] : inv_d * Ny[ur];
                accR = a;
            }
        }
        __syncthreads();   // before next chunk rewrites Ab/B
    }

    // ---- top-2 (lax.top_k tie-break: lower flat index wins)
    float v1 = -INFINITY, v2 = -INFINITY;
    int i1 = 0x7fffffff, i2 = 0x7fffffff;
    #pragma unroll
    for (int j = 0; j < 16; ++j) {
        float val = acc[j];
        int v = vg * 16 + j;
        int fl = (32 + uu) * D + (32 + v);
        if (better(val, fl, v1, i1)) { v2 = v1; i2 = i1; v1 = val; i1 = fl; }
        else if (better(val, fl, v2, i2)) { v2 = val; i2 = fl; }
    }
    if (tid < 129) {
        int fl = (32 + ur) * D + (32 + vr);
        if (better(accR, fl, v1, i1)) { v2 = v1; i2 = i1; v1 = accR; i1 = fl; }
        else if (better(accR, fl, v2, i2)) { v2 = accR; i2 = fl; }
    }
    for (int off = 32; off > 0; off >>= 1) {
        float b1 = __shfl_down(v1, off); int j1 = __shfl_down(i1, off);
        float b2 = __shfl_down(v2, off); int j2 = __shfl_down(i2, off);
        if (better(b1, j1, v1, i1)) {
            float nv2; int ni2;
            if (better(v1, i1, b2, j2)) { nv2 = v1; ni2 = i1; } else { nv2 = b2; ni2 = j2; }
            v1 = b1; i1 = j1; v2 = nv2; i2 = ni2;
        } else {
            if (better(b1, j1, v2, i2)) { v2 = b1; i2 = j1; }
        }
    }
    int wave = tid >> 6;
    if ((tid & 63) == 0) {
        redv[wave*2]   = v1; redi[wave*2]   = i1;
        redv[wave*2+1] = v2; redi[wave*2+1] = i2;
    }
    __syncthreads();
    if (tid == 0) {
        float r1 = -INFINITY, r2 = -INFINITY;
        int q1 = 0x7fffffff, q2 = 0x7fffffff;
        for (int i = 0; i < 8; ++i) {
            float val = redv[i]; int fl = redi[i];
            if (better(val, fl, r1, q1)) { r2 = r1; q2 = q1; r1 = val; q1 = fl; }
            else if (better(val, fl, r2, q2)) { r2 = val; q2 = fl; }
        }
        int base = bk * 2;
        outv[base]     = r1;
        outv[base + 1] = r2;
        float* os = outv + NB*NK*2;
        os[(base    )*2 + 0] = (float)(q1 / D - 64);
        os[(base    )*2 + 1] = (float)(q1 % D - 64);
        os[(base + 1)*2 + 0] = (float)(q2 / D - 64);
        os[(base + 1)*2 + 1] = (float)(q2 % D - 64);
    }
}

// ---------------- launcher ----------------

extern "C" void kernel_launch(void* const* d_in, const int* in_sizes, int n_in,
                              void* d_out, int out_size, void* d_ws, size_t ws_size,
                              hipStream_t stream) {
    const float* vol   = (const float*)d_in[0];   // (128,128,128)
    const float* parts = (const float*)d_in[1];   // (8,128,128)
    const float* ctf   = (const float*)d_in[2];   // (8,128,65)
    const float* euler = (const float*)d_in[3];   // (125,3)
    float* out = (float*)d_out;

    const int VOLC = D * SLAB;
    float2* bufA   = (float2*)d_ws;                    // vol x-pass out; later final vol_rfft
    float2* bufB   = bufA + VOLC;                      // vol y-pass out
    float2* pT1    = bufB + VOLC;                      // parts x-pass (8*SLAB)
    float2* QT     = pT1 + NB * SLAB;                  // parts_rfft shifted, transposed [b][x][m]
    float2* PJT    = QT + NB * W * D;                  // projs transposed [k][w][h]
    float*  CT     = (float*)(PJT + NK * W * D);       // ctf transposed [b][x][m]
    float*  rot    = CT + NB * W * D;                  // (125,9)

    // K1: vol x-FFT | parts x-FFT | rot | ctf transpose
    k1_kernel<<<1349, 256, 0, stream>>>(vol, parts, ctf, euler, bufA, pT1, CT, rot);
    // K2: vol y-FFT | parts y-FFT (transposed out)
    k2_kernel<<<553, 256, 0, stream>>>(bufA, bufB, pT1, QT);
    // K3: vol z-FFT
    k3_kernel<<<520, 256, 0, stream>>>(bufB, bufA);
    // K4: central-slice projections (transposed write)
    proj_kernel<<<(NK*D*W + 255) / 256, 256, 0, stream>>>(bufA, rot, PJT);
    // K5: fused correlation + windowed top-2
    corr_kernel<<<NB * NK, 256, 0, stream>>>(QT, CT, PJT, out);
}